// Round 8
// baseline (59.456 us; speedup 1.0000x reference)
//
#include <hip/hip_runtime.h>

// PathBundleChoiceScorer — reduced computation (verified rounds 1-7):
//   t1 = tanh(x @ W1^T); t2 = tanh(t1 @ W2^T); s[n] = dot(t2[n,:], Wout)
//   out[n] = top9-weighted collapse of {c_j*s}, c fixed {-1,0,+1} pattern.
// Round 8: kill the x cvt pass. GEMM1 stages A (x) as f32 via global_load_lds
// (128B half-rows, vrow = row*2+khalf, slot-XOR swizzle) and converts f32->f16
// at LDS read (RNE, bit-identical to round 4's pre-cvt). cvt kernel now does
// W1/W2 only. GEMM2 = round-4 kernel verbatim (fastest measured).

typedef __attribute__((ext_vector_type(4))) float     f32x4;
typedef __attribute__((ext_vector_type(8))) _Float16  f16x8;

#define AS1 __attribute__((address_space(1)))
#define AS3 __attribute__((address_space(3)))
#define GLOAD16(gp, lp) \
    __builtin_amdgcn_global_load_lds((AS1 const void*)(gp), (AS3 void*)(lp), 16, 0, 0)

// ---- f32 -> f16 convert: W1 (1M elems) + W2 (1M); 8 elems/thread ----------
__global__ __launch_bounds__(256)
void pbcs_cvt_w(const float* __restrict__ w1, _Float16* __restrict__ w1o,
                const float* __restrict__ w2, _Float16* __restrict__ w2o)
{
    const int b = blockIdx.x;
    const float* src; _Float16* dst; int idx;
    if (b < 512) { src = w1; dst = w1o; idx = b * 256 + threadIdx.x; }
    else         { src = w2; dst = w2o; idx = (b - 512) * 256 + threadIdx.x; }
    const float4 v0 = ((const float4*)src)[idx * 2];
    const float4 v1 = ((const float4*)src)[idx * 2 + 1];
    f16x8 h;
    h[0] = (_Float16)v0.x; h[1] = (_Float16)v0.y;
    h[2] = (_Float16)v0.z; h[3] = (_Float16)v0.w;
    h[4] = (_Float16)v1.x; h[5] = (_Float16)v1.y;
    h[6] = (_Float16)v1.z; h[7] = (_Float16)v1.w;
    ((f16x8*)dst)[idx] = h;
}

// ---- GEMM1: t1 = tanh(x @ W1^T), A = x f32 staged, B = W1 f16 --------------
// 256 threads = 4 waves (2m x 2n), block 128x128, wave 64x64, BK=64, 16 tiles.
// LDS/buf: A 32KB (256 vrows x 128B; vrow = row*2 + khalf) + B 16KB. dbuf 96KB.
__global__ __launch_bounds__(256, 1)
void pbcs_gemm_xf32(const float* __restrict__ A, const _Float16* __restrict__ B,
                    _Float16* __restrict__ Cout)
{
    extern __shared__ char smem[];    // 2 x 49152

    const int tid  = threadIdx.x;
    const int lane = tid & 63;
    const int wid  = tid >> 6;
    const int wm   = wid >> 1;
    const int wn   = wid & 1;
    const int l15  = lane & 15;
    const int g    = lane >> 4;
    const int m7   = l15 & 7;

    const int b  = blockIdx.x;                     // 0..255
    const int bm = (b & 7) * 4 + ((b >> 3) & 3);   // XCD-bijective
    const int bn = b >> 5;

    // ---- staging ----
    // A: 32 chunks of 1KB (8 vrows x 128B each); chunk c -> vrows c*8..c*8+7.
    //    vrow = row*2 + khalf; slot s holds global 16B-slot s ^ (row & 7).
    // B: 16 chunks of 1KB (8 rows x 128B, full BK=64 f16), round-4 pattern.
    const int r = lane >> 3, s = lane & 7;
    const char* aS[8]; int aD[8];
#pragma unroll
    for (int j = 0; j < 8; ++j) {
        const int c    = wid * 8 + j;
        const int row4 = c * 4 + (r >> 1);         // row in tile 0..127
        const int kh   = r & 1;
        aS[j] = (const char*)A + (size_t)(bm * 128 + row4) * 4096
              + kh * 128 + 16 * (s ^ (row4 & 7));
        aD[j] = c * 1024;
    }
    const char* bS[4]; int bD[4];
#pragma unroll
    for (int j = 0; j < 4; ++j) {
        const int c  = wid * 4 + j;
        const int rr = c * 8 + r;
        bS[j] = (const char*)B + (size_t)(bn * 128 + rr) * 2048 + 16 * (s ^ (rr & 7));
        bD[j] = 32768 + c * 1024;
    }

#define STAGE1(buf, kt) do {                                         \
        char* _D = smem + (buf) * 49152;                             \
        _Pragma("unroll")                                            \
        for (int _j = 0; _j < 8; ++_j)                               \
            GLOAD16(aS[_j] + (kt) * 256, _D + aD[_j]);               \
        _Pragma("unroll")                                            \
        for (int _j = 0; _j < 4; ++_j)                               \
            GLOAD16(bS[_j] + (kt) * 128, _D + bD[_j]);               \
    } while (0)

    // ---- LDS read offsets ----
    // A frag (mf,kh): global slots u=2g,2g+1 in vrow=arow*2+kh ->
    //   lds slot t = u ^ (arow&7);  second read = first ^ 16.
    int aoff[4][2], boff[4][2];
#pragma unroll
    for (int f = 0; f < 4; ++f) {
        const int arow = wm * 64 + f * 16 + l15;
        const int brow = wn * 64 + f * 16 + l15;
#pragma unroll
        for (int kh = 0; kh < 2; ++kh) {
            aoff[f][kh] = arow * 256 + kh * 128 + 16 * ((2 * g) ^ m7);
            boff[f][kh] = 32768 + brow * 128 + 16 * (((kh << 2) | g) ^ (brow & 7));
        }
    }

    f32x4 acc[4][4];
#pragma unroll
    for (int i = 0; i < 4; ++i)
#pragma unroll
        for (int j = 0; j < 4; ++j) acc[i][j] = (f32x4)0.f;

#define COMPUTE1(buf) do {                                                       \
        const char* _L = smem + (buf) * 49152;                                   \
        _Pragma("unroll")                                                        \
        for (int _kh = 0; _kh < 2; ++_kh) {                                      \
            f16x8 _a[4], _b[4];                                                  \
            _Pragma("unroll")                                                    \
            for (int _f = 0; _f < 4; ++_f) {                                     \
                const f32x4 _x0 = *(const f32x4*)(_L + aoff[_f][_kh]);           \
                const f32x4 _x1 = *(const f32x4*)(_L + (aoff[_f][_kh] ^ 16));    \
                _Pragma("unroll")                                                \
                for (int _e = 0; _e < 4; ++_e) {                                 \
                    _a[_f][_e]     = (_Float16)_x0[_e];                          \
                    _a[_f][_e + 4] = (_Float16)_x1[_e];                          \
                }                                                                \
                _b[_f] = *(const f16x8*)(_L + boff[_f][_kh]);                    \
            }                                                                    \
            _Pragma("unroll")                                                    \
            for (int _mf = 0; _mf < 4; ++_mf)                                    \
            _Pragma("unroll")                                                    \
            for (int _nf = 0; _nf < 4; ++_nf)                                    \
                acc[_mf][_nf] = __builtin_amdgcn_mfma_f32_16x16x32_f16(          \
                    _a[_mf], _b[_nf], acc[_mf][_nf], 0, 0, 0);                   \
        }                                                                        \
    } while (0)

    STAGE1(0, 0);
    STAGE1(1, 1);
#pragma unroll 1
    for (int t = 0; t < 15; ++t) {
        asm volatile("s_waitcnt vmcnt(12)" ::: "memory");
        __builtin_amdgcn_s_barrier();
        __builtin_amdgcn_sched_barrier(0);
        COMPUTE1(t & 1);
        asm volatile("s_waitcnt lgkmcnt(0)" ::: "memory");
        __builtin_amdgcn_sched_barrier(0);
        __builtin_amdgcn_s_barrier();
        if (t < 14) STAGE1(t & 1, t + 2);
    }
    asm volatile("s_waitcnt vmcnt(0)" ::: "memory");
    __builtin_amdgcn_s_barrier();
    __builtin_amdgcn_sched_barrier(0);
    COMPUTE1(1);   // t = 15

#pragma unroll
    for (int mf = 0; mf < 4; ++mf)
#pragma unroll
    for (int nf = 0; nf < 4; ++nf)
#pragma unroll
    for (int jj = 0; jj < 4; ++jj) {
        const int row = bm * 128 + wm * 64 + mf * 16 + g * 4 + jj;
        const int col = bn * 128 + wn * 64 + nf * 16 + l15;
        Cout[(size_t)row * 1024 + col] = (_Float16)tanhf(acc[mf][nf][jj]);
    }
#undef STAGE1
#undef COMPUTE1
}

// ---- GEMM2 (round-4 verbatim): s_part fused wout dot ------------------------
__global__ __launch_bounds__(256, 2)
void pbcs_gemm2(const _Float16* __restrict__ A, const _Float16* __restrict__ B,
                const float* __restrict__ wout, float* __restrict__ s_part)
{
    __shared__ char smem[2][32768];   // [buf][ A 16K | B 16K ]

    const int tid  = threadIdx.x;
    const int lane = tid & 63;
    const int wid  = tid >> 6;
    const int wm   = wid >> 1;
    const int wn   = wid & 1;
    const int l15  = lane & 15;
    const int g    = lane >> 4;

    const int b  = blockIdx.x;
    const int bm = (b & 7) * 4 + ((b >> 3) & 3);
    const int bn = b >> 5;

    const char* aS[4]; const char* bS[4]; int aD[4], bD[4];
#pragma unroll
    for (int j = 0; j < 4; ++j) {
        const int c = wid * 4 + j;
        const int r = c * 8 + (lane >> 3), s = lane & 7;
        aS[j] = (const char*)A + (size_t)(bm * 128 + r) * 2048 + 16 * (s ^ (r & 7));
        aD[j] = c * 1024;
        bS[j] = (const char*)B + (size_t)(bn * 128 + r) * 2048 + 16 * (s ^ (r & 7));
        bD[j] = 16384 + c * 1024;
    }

    int aoff[4][2], boff[4][2];
#pragma unroll
    for (int f = 0; f < 4; ++f) {
        const int ra = wm * 64 + f * 16 + l15;
        const int rb = wn * 64 + f * 16 + l15;
#pragma unroll
        for (int kh = 0; kh < 2; ++kh) {
            aoff[f][kh] = ra * 128 + 16 * (((kh << 2) | g) ^ (ra & 7));
            boff[f][kh] = 16384 + rb * 128 + 16 * (((kh << 2) | g) ^ (rb & 7));
        }
    }

    f32x4 acc[4][4];
#pragma unroll
    for (int i = 0; i < 4; ++i)
#pragma unroll
        for (int j = 0; j < 4; ++j) acc[i][j] = (f32x4)0.f;

#define STAGE2(buf, kt) do {                                     \
        const int _ko = (kt) * 128;                              \
        _Pragma("unroll")                                        \
        for (int _j = 0; _j < 4; ++_j) {                         \
            GLOAD16(aS[_j] + _ko, smem[buf] + aD[_j]);           \
            GLOAD16(bS[_j] + _ko, smem[buf] + bD[_j]);           \
        }                                                        \
    } while (0)

#define COMPUTE2(buf) do {                                                       \
        _Pragma("unroll")                                                        \
        for (int _kh = 0; _kh < 2; ++_kh) {                                      \
            f16x8 _a[4], _b[4];                                                  \
            _Pragma("unroll")                                                    \
            for (int _f = 0; _f < 4; ++_f) {                                     \
                _a[_f] = *(const f16x8*)(smem[buf] + aoff[_f][_kh]);             \
                _b[_f] = *(const f16x8*)(smem[buf] + boff[_f][_kh]);             \
            }                                                                    \
            _Pragma("unroll")                                                    \
            for (int _mf = 0; _mf < 4; ++_mf)                                    \
            _Pragma("unroll")                                                    \
            for (int _nf = 0; _nf < 4; ++_nf)                                    \
                acc[_mf][_nf] = __builtin_amdgcn_mfma_f32_16x16x32_f16(          \
                    _a[_mf], _b[_nf], acc[_mf][_nf], 0, 0, 0);                   \
        }                                                                        \
    } while (0)

    STAGE2(0, 0);
    STAGE2(1, 1);
#pragma unroll 1
    for (int t = 0; t < 15; ++t) {
        asm volatile("s_waitcnt vmcnt(8)" ::: "memory");
        __builtin_amdgcn_s_barrier();
        __builtin_amdgcn_sched_barrier(0);
        COMPUTE2(t & 1);
        asm volatile("s_waitcnt lgkmcnt(0)" ::: "memory");
        __builtin_amdgcn_sched_barrier(0);
        __builtin_amdgcn_s_barrier();
        if (t < 14) STAGE2(t & 1, t + 2);
    }
    asm volatile("s_waitcnt vmcnt(0)" ::: "memory");
    __builtin_amdgcn_s_barrier();
    __builtin_amdgcn_sched_barrier(0);
    COMPUTE2(1);   // t = 15

    float w[4];
#pragma unroll
    for (int nf = 0; nf < 4; ++nf)
        w[nf] = wout[bn * 128 + wn * 64 + nf * 16 + l15];
#pragma unroll
    for (int mf = 0; mf < 4; ++mf)
#pragma unroll
    for (int jj = 0; jj < 4; ++jj) {
        float v = 0.f;
#pragma unroll
        for (int nf = 0; nf < 4; ++nf)
            v += tanhf(acc[mf][nf][jj]) * w[nf];
        v += __shfl_xor(v, 1, 64);
        v += __shfl_xor(v, 2, 64);
        v += __shfl_xor(v, 4, 64);
        v += __shfl_xor(v, 8, 64);
        if (l15 == 0) {
            const int row = bm * 128 + wm * 64 + mf * 16 + g * 4 + jj;
            s_part[row * 16 + bn * 2 + wn] = v;
        }
    }
#undef STAGE2
#undef COMPUTE2
}

// ---- finalize: s = sum(s_part), then faithful 27-path top-9 collapse -------
__global__ __launch_bounds__(256)
void pbcs_finalize(const float* __restrict__ s_part,
                   const float* __restrict__ soa_w, const float* __restrict__ soa_b,
                   const float* __restrict__ sob_w, const float* __restrict__ sob_b,
                   float* __restrict__ out, int Nrows)
{
    const int row  = blockIdx.x * 4 + (threadIdx.x >> 6);
    const int lane = threadIdx.x & 63;
    if (row >= Nrows) return;

    float part = (lane < 16) ? s_part[row * 16 + lane] : 0.f;
#pragma unroll
    for (int off = 32; off > 0; off >>= 1) part += __shfl_xor(part, off, 64);
    const float s = part;

    const float C7 = 0.8975979010256552f;   // 2*pi/7
    float tS = 0.f, tZ = 0.f, tN = 0.f;
    if (lane < 32) {
        const float aw = soa_w[lane];
        const float ab = soa_b[lane];
        const float bw = sob_w[lane];
        tS = bw * sinf(C7 * fmaf(aw,  s, ab));
        tZ = bw * sinf(C7 * ab);
        tN = bw * sinf(C7 * fmaf(aw, -s, ab));
    }
#pragma unroll
    for (int off = 32; off > 0; off >>= 1) {
        tS += __shfl_xor(tS, off, 64);
        tZ += __shfl_xor(tZ, off, 64);
        tN += __shfl_xor(tN, off, 64);
    }
    const float bb = sob_b[0];
    const float fS = tS + bb;
    const float f0 = tZ + bb;
    const float fN = tN + bb;

    // 27 paths: P[k] = {1,0,-1,0,0,0,-1,0,1}; tri q: (-pos, 0, +pos)
    const int j  = lane;
    const int kk = j / 3;
    const int q  = j - kk * 3;
    const int p  = ((0x101 >> kk) & 1) - ((0x044 >> kk) & 1);
    const int c  = (q == 0) ? -p : ((q == 2) ? p : 0);
    const float val = (float)c * s;
    const float sc  = (c == 0) ? f0 : ((c > 0) ? fS : fN);

    int rank = 0;
#pragma unroll 1
    for (int i = 0; i < 27; ++i) {
        const float sci = __shfl(sc, i, 64);
        rank += (sci > sc) || (sci == sc && i < j);
    }
    const float mx = fmaxf(fS, fmaxf(f0, fN));
    float e = (j < 27 && rank < 9) ? expf(sc - mx) : 0.f;
    float num = val * e;
    float den = e;
#pragma unroll
    for (int off = 32; off > 0; off >>= 1) {
        num += __shfl_xor(num, off, 64);
        den += __shfl_xor(den, off, 64);
    }
    if (lane == 0) out[row] = num / den;
}

extern "C" void kernel_launch(void* const* d_in, const int* in_sizes, int n_in,
                              void* d_out, int out_size, void* d_ws, size_t ws_size,
                              hipStream_t stream)
{
    const float* x     = (const float*)d_in[0];
    const float* W1    = (const float*)d_in[1];
    const float* W2    = (const float*)d_in[2];
    const float* Wout  = (const float*)d_in[3];
    const float* soa_w = (const float*)d_in[12];
    const float* soa_b = (const float*)d_in[13];
    const float* sob_w = (const float*)d_in[14];
    const float* sob_b = (const float*)d_in[15];

    const int Nr = 4096;
    char* ws = (char*)d_ws;
    _Float16* t1f = (_Float16*)ws;                    //  8MB  [4096,1024]
    _Float16* w1f = (_Float16*)(ws + (8u  << 20));    //  2MB  [1024,1024]
    _Float16* w2f = (_Float16*)(ws + (10u << 20));    //  2MB  [1024,1024]
    float* s_part = (float*)(ws + (12u << 20));       //  256KB

    hipFuncSetAttribute((const void*)pbcs_gemm_xf32,
                        hipFuncAttributeMaxDynamicSharedMemorySize, 98304);

    pbcs_cvt_w<<<1024, 256, 0, stream>>>(W1, w1f, W2, w2f);

    pbcs_gemm_xf32<<<256, 256, 98304, stream>>>(x, w1f, t1f);
    pbcs_gemm2<<<256, 256, 0, stream>>>(t1f, w2f, Wout, s_part);

    pbcs_finalize<<<Nr / 4, 256, 0, stream>>>(s_part, soa_w, soa_b, sob_w, sob_b,
                                              (float*)d_out, Nr);
}

// Round 10
// 56.236 us; speedup vs baseline: 1.0573x; 1.0573x over previous
//
#include <hip/hip_runtime.h>

// PathBundleChoiceScorer — reduced computation (verified rounds 1-9):
//   t1 = tanh(x @ W1^T); t2 = tanh(t1 @ W2^T); s[n] = dot(t2[n,:], Wout)
//   out[n] = top9-weighted collapse of {c_j*s}, c fixed {-1,0,+1} pattern.
// Round 10: revert to the round-4 configuration (proven fastest, 56.4us).
// fp16 single-product MFMA GEMMs, 128x128 tile, 4 waves, BK=64, dbuf LDS,
// counted vmcnt(8), 8-slot XOR swizzle, XCD-bijective block swizzle.
// R9's cross-block split-K was WRONG (tanh of partial K-sums); R5-R8 showed
// every byte-increasing or schedule-only change is null or regresses.

typedef __attribute__((ext_vector_type(4))) float     f32x4;
typedef __attribute__((ext_vector_type(8))) _Float16  f16x8;

#define AS1 __attribute__((address_space(1)))
#define AS3 __attribute__((address_space(3)))
#define GLOAD16(gp, lp) \
    __builtin_amdgcn_global_load_lds((AS1 const void*)(gp), (AS3 void*)(lp), 16, 0, 0)

// ---- f32 -> f16 convert: x (4M elems), W1 (1M), W2 (1M); 8 elems/thread ----
__global__ __launch_bounds__(256)
void pbcs_cvt(const float* __restrict__ x,  _Float16* __restrict__ xo,
              const float* __restrict__ w1, _Float16* __restrict__ w1o,
              const float* __restrict__ w2, _Float16* __restrict__ w2o)
{
    const int b = blockIdx.x;
    const float* src; _Float16* dst; int idx;
    if (b < 2048)      { src = x;  dst = xo;  idx = b * 256 + threadIdx.x; }
    else if (b < 2560) { src = w1; dst = w1o; idx = (b - 2048) * 256 + threadIdx.x; }
    else               { src = w2; dst = w2o; idx = (b - 2560) * 256 + threadIdx.x; }
    const float4 v0 = ((const float4*)src)[idx * 2];
    const float4 v1 = ((const float4*)src)[idx * 2 + 1];
    f16x8 h;
    h[0] = (_Float16)v0.x; h[1] = (_Float16)v0.y;
    h[2] = (_Float16)v0.z; h[3] = (_Float16)v0.w;
    h[4] = (_Float16)v1.x; h[5] = (_Float16)v1.y;
    h[6] = (_Float16)v1.z; h[7] = (_Float16)v1.w;
    ((f16x8*)dst)[idx] = h;
}

// ---- fp16 MFMA GEMM:  C = A @ B^T, A [4096,1024] f16, B [1024,1024] f16 ----
// 256 threads = 4 waves (2m x 2n), wave tile 64x64, BK=64, 16 k-tiles.
// EPI=0: Cout = tanh(acc) as f16.  EPI=1: s_part += fused wout dot.
template<int EPI>
__global__ __launch_bounds__(256, 2)
void pbcs_gemm16(const _Float16* __restrict__ A, const _Float16* __restrict__ B,
                 _Float16* __restrict__ Cout, const float* __restrict__ wout,
                 float* __restrict__ s_part)
{
    __shared__ char smem[2][32768];   // [buf][ A 16K | B 16K ]

    const int tid  = threadIdx.x;
    const int lane = tid & 63;
    const int wid  = tid >> 6;
    const int wm   = wid >> 1;
    const int wn   = wid & 1;
    const int l15  = lane & 15;
    const int g    = lane >> 4;       // k-group 0..3

    // bijective XCD swizzle: XCD (= blk%8) owns a contiguous bm-stripe
    const int b  = blockIdx.x;                     // 0..255
    const int bm = (b & 7) * 4 + ((b >> 3) & 3);   // 0..31
    const int bn = b >> 5;                         // 0..7

    // ---- staging: 32 chunks of 1KB (16 A + 16 B), 8 per wave ----
    // chunk c covers rows c*8..c*8+7 (128B/row = 64 f16); linear LDS dest,
    // pre-swizzled global source (slot s holds k-group s^(row&7)).
    const char* aS[4]; const char* bS[4]; int aD[4], bD[4];
#pragma unroll
    for (int j = 0; j < 4; ++j) {
        const int c = wid * 4 + j;
        const int r = c * 8 + (lane >> 3), s = lane & 7;
        aS[j] = (const char*)A + (size_t)(bm * 128 + r) * 2048 + 16 * (s ^ (r & 7));
        aD[j] = c * 1024;
        bS[j] = (const char*)B + (size_t)(bn * 128 + r) * 2048 + 16 * (s ^ (r & 7));
        bD[j] = 16384 + c * 1024;
    }

    // ---- LDS read offsets (swizzled) ----
    int aoff[4][2], boff[4][2];
#pragma unroll
    for (int f = 0; f < 4; ++f) {
        const int ra = wm * 64 + f * 16 + l15;
        const int rb = wn * 64 + f * 16 + l15;
#pragma unroll
        for (int kh = 0; kh < 2; ++kh) {
            aoff[f][kh] = ra * 128 + 16 * (((kh << 2) | g) ^ (ra & 7));
            boff[f][kh] = 16384 + rb * 128 + 16 * (((kh << 2) | g) ^ (rb & 7));
        }
    }

    f32x4 acc[4][4];
#pragma unroll
    for (int i = 0; i < 4; ++i)
#pragma unroll
        for (int j = 0; j < 4; ++j) acc[i][j] = (f32x4)0.f;

#define STAGE(buf, kt) do {                                      \
        const int _ko = (kt) * 128;                              \
        _Pragma("unroll")                                        \
        for (int _j = 0; _j < 4; ++_j) {                         \
            GLOAD16(aS[_j] + _ko, smem[buf] + aD[_j]);           \
            GLOAD16(bS[_j] + _ko, smem[buf] + bD[_j]);           \
        }                                                        \
    } while (0)

#define COMPUTE(buf) do {                                                        \
        _Pragma("unroll")                                                        \
        for (int _kh = 0; _kh < 2; ++_kh) {                                      \
            f16x8 _a[4], _b[4];                                                  \
            _Pragma("unroll")                                                    \
            for (int _f = 0; _f < 4; ++_f) {                                     \
                _a[_f] = *(const f16x8*)(smem[buf] + aoff[_f][_kh]);             \
                _b[_f] = *(const f16x8*)(smem[buf] + boff[_f][_kh]);             \
            }                                                                    \
            _Pragma("unroll")                                                    \
            for (int _mf = 0; _mf < 4; ++_mf)                                    \
            _Pragma("unroll")                                                    \
            for (int _nf = 0; _nf < 4; ++_nf)                                    \
                acc[_mf][_nf] = __builtin_amdgcn_mfma_f32_16x16x32_f16(          \
                    _a[_mf], _b[_nf], acc[_mf][_nf], 0, 0, 0);                   \
        }                                                                        \
    } while (0)

    // ---- double-buffered counted-vmcnt loop over 16 k-tiles ----
    STAGE(0, 0);
    STAGE(1, 1);
#pragma unroll 1
    for (int t = 0; t < 15; ++t) {
        asm volatile("s_waitcnt vmcnt(8)" ::: "memory");  // k-tile t landed
        __builtin_amdgcn_s_barrier();
        __builtin_amdgcn_sched_barrier(0);
        COMPUTE(t & 1);
        asm volatile("s_waitcnt lgkmcnt(0)" ::: "memory");
        __builtin_amdgcn_sched_barrier(0);
        __builtin_amdgcn_s_barrier();                     // all reads of buf done
        if (t < 14) STAGE(t & 1, t + 2);
    }
    asm volatile("s_waitcnt vmcnt(0)" ::: "memory");
    __builtin_amdgcn_s_barrier();
    __builtin_amdgcn_sched_barrier(0);
    COMPUTE(1);   // t = 15

    // ---- epilogue ----
    if (EPI == 0) {
#pragma unroll
        for (int mf = 0; mf < 4; ++mf)
#pragma unroll
        for (int nf = 0; nf < 4; ++nf)
#pragma unroll
        for (int jj = 0; jj < 4; ++jj) {
            const int row = bm * 128 + wm * 64 + mf * 16 + g * 4 + jj;
            const int col = bn * 128 + wn * 64 + nf * 16 + l15;
            Cout[(size_t)row * 1024 + col] = (_Float16)tanhf(acc[mf][nf][jj]);
        }
    } else {
        float w[4];
#pragma unroll
        for (int nf = 0; nf < 4; ++nf)
            w[nf] = wout[bn * 128 + wn * 64 + nf * 16 + l15];
#pragma unroll
        for (int mf = 0; mf < 4; ++mf)
#pragma unroll
        for (int jj = 0; jj < 4; ++jj) {
            float v = 0.f;
#pragma unroll
            for (int nf = 0; nf < 4; ++nf)
                v += tanhf(acc[mf][nf][jj]) * w[nf];
            v += __shfl_xor(v, 1, 64);
            v += __shfl_xor(v, 2, 64);
            v += __shfl_xor(v, 4, 64);
            v += __shfl_xor(v, 8, 64);
            if (l15 == 0) {
                const int row = bm * 128 + wm * 64 + mf * 16 + g * 4 + jj;
                s_part[row * 16 + bn * 2 + wn] = v;
            }
        }
    }
#undef STAGE
#undef COMPUTE
}

// ---- finalize: s = sum(s_part), then faithful 27-path top-9 collapse -------
__global__ __launch_bounds__(256)
void pbcs_finalize(const float* __restrict__ s_part,
                   const float* __restrict__ soa_w, const float* __restrict__ soa_b,
                   const float* __restrict__ sob_w, const float* __restrict__ sob_b,
                   float* __restrict__ out, int Nrows)
{
    const int row  = blockIdx.x * 4 + (threadIdx.x >> 6);
    const int lane = threadIdx.x & 63;
    if (row >= Nrows) return;

    float part = (lane < 16) ? s_part[row * 16 + lane] : 0.f;
#pragma unroll
    for (int off = 32; off > 0; off >>= 1) part += __shfl_xor(part, off, 64);
    const float s = part;

    const float C7 = 0.8975979010256552f;   // 2*pi/7
    float tS = 0.f, tZ = 0.f, tN = 0.f;
    if (lane < 32) {
        const float aw = soa_w[lane];
        const float ab = soa_b[lane];
        const float bw = sob_w[lane];
        tS = bw * sinf(C7 * fmaf(aw,  s, ab));
        tZ = bw * sinf(C7 * ab);
        tN = bw * sinf(C7 * fmaf(aw, -s, ab));
    }
#pragma unroll
    for (int off = 32; off > 0; off >>= 1) {
        tS += __shfl_xor(tS, off, 64);
        tZ += __shfl_xor(tZ, off, 64);
        tN += __shfl_xor(tN, off, 64);
    }
    const float bb = sob_b[0];
    const float fS = tS + bb;
    const float f0 = tZ + bb;
    const float fN = tN + bb;

    // 27 paths: P[k] = {1,0,-1,0,0,0,-1,0,1}; tri q: (-pos, 0, +pos)
    const int j  = lane;
    const int kk = j / 3;
    const int q  = j - kk * 3;
    const int p  = ((0x101 >> kk) & 1) - ((0x044 >> kk) & 1);
    const int c  = (q == 0) ? -p : ((q == 2) ? p : 0);
    const float val = (float)c * s;
    const float sc  = (c == 0) ? f0 : ((c > 0) ? fS : fN);

    int rank = 0;
#pragma unroll 1
    for (int i = 0; i < 27; ++i) {
        const float sci = __shfl(sc, i, 64);
        rank += (sci > sc) || (sci == sc && i < j);
    }
    const float mx = fmaxf(fS, fmaxf(f0, fN));
    float e = (j < 27 && rank < 9) ? expf(sc - mx) : 0.f;
    float num = val * e;
    float den = e;
#pragma unroll
    for (int off = 32; off > 0; off >>= 1) {
        num += __shfl_xor(num, off, 64);
        den += __shfl_xor(den, off, 64);
    }
    if (lane == 0) out[row] = num / den;
}

extern "C" void kernel_launch(void* const* d_in, const int* in_sizes, int n_in,
                              void* d_out, int out_size, void* d_ws, size_t ws_size,
                              hipStream_t stream)
{
    const float* x     = (const float*)d_in[0];
    const float* W1    = (const float*)d_in[1];
    const float* W2    = (const float*)d_in[2];
    const float* Wout  = (const float*)d_in[3];
    const float* soa_w = (const float*)d_in[12];
    const float* soa_b = (const float*)d_in[13];
    const float* sob_w = (const float*)d_in[14];
    const float* sob_b = (const float*)d_in[15];

    const int Nr = 4096;
    char* ws = (char*)d_ws;
    _Float16* xf  = (_Float16*)ws;                    //  8MB  [4096,1024]
    _Float16* t1f = (_Float16*)(ws + (8u  << 20));    //  8MB  [4096,1024]
    _Float16* w1f = (_Float16*)(ws + (16u << 20));    //  2MB  [1024,1024]
    _Float16* w2f = (_Float16*)(ws + (18u << 20));    //  2MB  [1024,1024]
    float* s_part = (float*)(ws + (20u << 20));       //  256KB

    pbcs_cvt<<<3072, 256, 0, stream>>>(x, xf, W1, w1f, W2, w2f);

    pbcs_gemm16<0><<<256, 256, 0, stream>>>(xf,  w1f, t1f, nullptr, nullptr);
    pbcs_gemm16<1><<<256, 256, 0, stream>>>(t1f, w2f, nullptr, Wout, s_part);

    pbcs_finalize<<<Nr / 4, 256, 0, stream>>>(s_part, soa_w, soa_b, sob_w, sob_b,
                                              (float*)d_out, Nr);
}